// Round 9
// baseline (193.918 us; speedup 1.0000x reference)
//
#include <hip/hip_runtime.h>
#include <math.h>

typedef _Float16 f16;
typedef _Float16 f16x2 __attribute__((ext_vector_type(2)));
typedef _Float16 f16x4 __attribute__((ext_vector_type(4)));
typedef _Float16 f16x8 __attribute__((ext_vector_type(8)));
typedef float    f32x4  __attribute__((ext_vector_type(4)));
typedef float    f32x16 __attribute__((ext_vector_type(16)));

#define PKRTZ(a, b) __builtin_bit_cast(f16x2, __builtin_amdgcn_cvt_pkrtz((a), (b)))
#define MFMA32(a, b, c) __builtin_amdgcn_mfma_f32_32x32x16_f16((a), (b), (c), 0, 0, 0)

#define NN 8192
#define DD 64
#define KT 32
#define NWAVES 4               // 4 key-split waves per block
#define KPW (NN / NWAVES)      // 2048 keys per wave
#define NTILES (KPW / KT)      // 64
#define NQB 32                 // queries per block (one 32-q MFMA block)

#define LOG2E 1.44269504088896f

// sigma: key-order permutation inside each 32-key tile (self-inverse).
// Makes the 32x32 QK C-layout rows, packed pairwise, directly a valid
// PV A-operand fragment (no cross-lane exchange needed).
__device__ __forceinline__ int sig32(int k) {
  const int g = (k >> 2) & 3;
  return (g == 1 || g == 2) ? (k ^ 12) : k;
}

// ---------------- kernel A: f32 -> fragment-streamed f16 workspaces ----------------
// Workspace layouts are LANE-ORDER STREAMS so kernel B's fragment loads are
// fully coalesced (1024 B contiguous per wave instruction).
//   Xk[b][kt][c(4)][lane(64)][8 f16]   chunk(c,lane): Ksig[l31][c*16+hi*8+j]
//   Xv[b][kt][i(4)][lane(64)][8 f16]   chunk(i=db*2+kh,lane): V[db*32+l31][kh*16+hi*8+j]
__global__ __launch_bounds__(256, 2)
void prep_f16(const float* __restrict__ X, f16* __restrict__ Xk, f16* __restrict__ Xv)
{
  __shared__ f16 Lt[64 * 72];          // 64 keys x 64 d, pitch 72 (natural order)
  const int tid  = threadIdx.x;
  const int b    = blockIdx.x >> 7;
  const int kb64 = (blockIdx.x & 127) * 64;

  // phase 1: coalesced read, cvt, stash in LDS
  {
    const int r = tid >> 2;            // key row 0..63
    const int c = (tid & 3) * 16;      // d col group
    const float* p = X + ((size_t)(b * NN + kb64 + r)) * DD + c;
    const float4 a0 = *(const float4*)(p);
    const float4 a1 = *(const float4*)(p + 4);
    const float4 a2 = *(const float4*)(p + 8);
    const float4 a3 = *(const float4*)(p + 12);
    f16x8 v0, v1;
    v0[0]=(f16)a0.x; v0[1]=(f16)a0.y; v0[2]=(f16)a0.z; v0[3]=(f16)a0.w;
    v0[4]=(f16)a1.x; v0[5]=(f16)a1.y; v0[6]=(f16)a1.z; v0[7]=(f16)a1.w;
    v1[0]=(f16)a2.x; v1[1]=(f16)a2.y; v1[2]=(f16)a2.z; v1[3]=(f16)a2.w;
    v1[4]=(f16)a3.x; v1[5]=(f16)a3.y; v1[6]=(f16)a3.z; v1[7]=(f16)a3.w;
    *(f16x8*)&Lt[r * 72 + c]     = v0;
    *(f16x8*)&Lt[r * 72 + c + 8] = v1;
  }
  __syncthreads();

  // phase 2a: K fragment stream (vector LDS reads, coalesced global writes)
  #pragma unroll
  for (int i = 0; i < 2; ++i) {
    const int gc  = i * 256 + tid;     // 0..511 (2 tiles x 256 chunks)
    const int h   = gc >> 8;           // which 32-key tile of the 64
    const int ci  = gc & 255;          // chunk within tile
    const int c   = ci >> 6;           // d-chunk 0..3
    const int ln  = ci & 63;           // lane
    const int hi  = ln >> 5;
    const int l31 = ln & 31;
    const int row = h * 32 + sig32(l31);
    const f16x8 v = *(const f16x8*)&Lt[row * 72 + c * 16 + hi * 8];
    const int kt  = (kb64 >> 5) + h;
    *(f16x8*)(Xk + ((size_t)(b * (NN/32) + kt)) * 2048 + ci * 8) = v;
  }

  // phase 2b: V fragment stream (transpose via scalar LDS reads)
  #pragma unroll
  for (int i = 0; i < 2; ++i) {
    const int gc  = i * 256 + tid;
    const int h   = gc >> 8;
    const int ci  = gc & 255;
    const int ins = ci >> 6;           // db*2 + kh
    const int db  = ins >> 1;
    const int kh  = ins & 1;
    const int ln  = ci & 63;
    const int hi  = ln >> 5;
    const int l31 = ln & 31;
    union { f16 s[8]; f16x8 v; } u;
    #pragma unroll
    for (int j = 0; j < 8; ++j)
      u.s[j] = Lt[(h*32 + kh*16 + hi*8 + j) * 72 + db*32 + l31];
    const int kt = (kb64 >> 5) + h;
    *(f16x8*)(Xv + ((size_t)(b * (NN/32) + kt)) * 2048 + ci * 8) = u.v;
  }
}

// ---------------- kernel B: attention + projection ----------------
// NEW (R9): query-split for occupancy. Wave = 32 queries x 2048 keys; block =
// 4 key-split waves (same 32 q); grid = 4 batches x 256 qgroups = 1024 blocks
// -> 4096 waves = 4 waves/SIMD (was grid-limited at 2). acc halves to 32 regs;
// __launch_bounds__(256,4) caps VGPR at 128 (the occupancy quantum) under
// either toolchain interpretation of the 2nd arg.
#define HP2      36                      // Hl pitch (32 q + pad)
#define WL2_OFF  (64 * HP2 * 4)          // 9216
#define LST2_OFF (WL2_OFF + 64 * 68 * 4) // 26624
#define SMEM2_B  (LST2_OFF + 32 * 4)     // 26752

__global__ __launch_bounds__(256, 4)
void gconv_attn(const float* __restrict__ X, const f16* __restrict__ Xk,
                const f16* __restrict__ Xv, const float* __restrict__ W,
                float* __restrict__ out)
{
  __shared__ __align__(16) unsigned char smem[SMEM2_B];

  const int tid  = threadIdx.x;
  const int lane = tid & 63;
  const int wave = tid >> 6;          // key split 0..3
  const int l31  = lane & 31;
  const int hi   = lane >> 5;

  // ---- XCD-aware decode: one batch per XCD pair (1024 = 8 xcd * 128 slots) ----
  const int xcd   = blockIdx.x & 7;
  const int slot  = blockIdx.x >> 3;          // 0..127
  const int batch = xcd >> 1;
  const int qblk  = slot * 2 + (xcd & 1);     // 0..255, bijective
  const int qbase = qblk * NQB;
  const float* Xb = X + (size_t)batch * NN * DD;

  // wave-local bases: lane-order streams (lane*8 folded in)
  const f16* XkW = Xk + ((size_t)batch * (NN/32) + wave * NTILES) * 2048 + lane * 8;
  const f16* XvW = Xv + ((size_t)batch * (NN/32) + wave * NTILES) * 2048 + lane * 8;

  // ---- Q fragment (B-operand: n=l31 query, k=c*16+hi*8+j d), exp2 domain ----
  // -(m2) folded into the MFMA C-initializer minit (f32x16 broadcast).
  f16x8 qf[4];
  f32x16 minit;
  float lrow = 0.f;
  {
    const float* qp = Xb + (size_t)(qbase + l31) * DD + hi*8;
    float nrm = 0.f;
    #pragma unroll
    for (int c = 0; c < 4; ++c) {
      const float4 a = *(const float4*)(qp + c*16);
      const float4 b = *(const float4*)(qp + c*16 + 4);
      float xs[8] = {a.x, a.y, a.z, a.w, b.x, b.y, b.z, b.w};
      f16x8 v;
      #pragma unroll
      for (int e = 0; e < 8; ++e) {
        const f16 kv = (f16)xs[e];
        const f16 qs = (f16)(xs[e] * LOG2E);
        nrm += (float)qs * (float)kv;
        v[e] = qs;
      }
      qf[c] = v;
    }
    nrm += __shfl_xor(nrm, 32);
    const float m2 = nrm + 2.0f;
    #pragma unroll
    for (int e = 0; e < 16; ++e) minit[e] = -m2;
  }

  f32x16 acc[2];
  #pragma unroll
  for (int a = 0; a < 2; ++a)
    #pragma unroll
    for (int e = 0; e < 16; ++e) acc[a][e] = 0.f;

  const f16x2 kOnes = (f16x2){(f16)1.0f, (f16)1.0f};

  f16x8 ka[4];          // K A-operand: 4 d-chunks of 16
  f16x8 vb[2][2];       // V B-operand: [d-block][k-half]

  auto LDK = [&](int t) {
    const f16* kn = XkW + (size_t)t * 2048;
    #pragma unroll
    for (int c = 0; c < 4; ++c)
      ka[c] = *(const f16x8*)(kn + c * 512);   // 1024 B contiguous per wave
  };
  auto LDV = [&](int t) {
    const f16* vn = XvW + (size_t)t * 2048;
    #pragma unroll
    for (int db = 0; db < 2; ++db)
      #pragma unroll
      for (int kh = 0; kh < 2; ++kh)
        vb[db][kh] = *(const f16x8*)(vn + (db*2 + kh) * 512);
  };

  // softmax+pack: s (C-layout, sigma-ordered keys) -> two PV A-fragments
  auto SMpack = [&](const f32x16& s, float& lr, f16x8& paLo, f16x8& paHi) {
    float p[16];
    #pragma unroll
    for (int r = 0; r < 16; ++r) p[r] = __builtin_amdgcn_exp2f(s[r]);
    union { f16x8 v; f16x2 h[4]; } a, b;
    a.h[0] = PKRTZ(p[0],  p[1]);  a.h[1] = PKRTZ(p[2],  p[3]);
    a.h[2] = PKRTZ(p[4],  p[5]);  a.h[3] = PKRTZ(p[6],  p[7]);
    b.h[0] = PKRTZ(p[8],  p[9]);  b.h[1] = PKRTZ(p[10], p[11]);
    b.h[2] = PKRTZ(p[12], p[13]); b.h[3] = PKRTZ(p[14], p[15]);
    #pragma unroll
    for (int i = 0; i < 4; ++i) {
      lr = __builtin_amdgcn_fdot2(a.h[i], kOnes, lr, false);
      lr = __builtin_amdgcn_fdot2(b.h[i], kOnes, lr, false);
    }
    paLo = a.v; paHi = b.v;
  };

  // ---- main loop: QK -> pack -> PV, all in registers; 1-tile-ahead loads ----
  LDK(0);
  LDV(0);
  for (int t = 0; t < NTILES; ++t) {
    const int tn = (t + 1 < NTILES) ? t + 1 : t;

    f32x16 s = MFMA32(ka[0], qf[0], minit);
    s = MFMA32(ka[1], qf[1], s);
    s = MFMA32(ka[2], qf[2], s);
    s = MFMA32(ka[3], qf[3], s);

    LDK(tn);                      // ka dead; prefetch next tile's K

    f16x8 pa0, pa1;
    SMpack(s, lrow, pa0, pa1);

    acc[0] = MFMA32(pa0, vb[0][0], acc[0]);
    acc[0] = MFMA32(pa1, vb[0][1], acc[0]);
    acc[1] = MFMA32(pa0, vb[1][0], acc[1]);
    acc[1] = MFMA32(pa1, vb[1][1], acc[1]);

    LDV(tn);                      // vb dead; prefetch next tile's V
  }

  // ========= merge across 4 key-split waves (shared m2: plain sums) =========
  __syncthreads();
  float* Hl    = (float*)smem;                   // [64 d][HP2 q]
  float* Wl    = (float*)(smem + WL2_OFF);       // [64 d][68]
  float* Lstar = (float*)(smem + LST2_OFF);      // [32 q]

  for (int i = tid; i < 64*HP2; i += 256) Hl[i] = 0.f;
  for (int i = tid; i < 64*64; i += 256) Wl[(i >> 6)*68 + (i & 63)] = W[i];
  if (tid < 32) Lstar[tid] = 0.f;
  __syncthreads();

  // acc C-layout: col = l31 = d (within 32-block), row ql = (r&3)+8*(r>>2)+4*hi
  {
    float lr = lrow;
    lr += __shfl_xor(lr, 32);
    if (lane < 32) atomicAdd(&Lstar[lane], lr);
    #pragma unroll
    for (int db = 0; db < 2; ++db)
      #pragma unroll
      for (int r = 0; r < 16; ++r) {
        const int ql = (r & 3) + 8*(r >> 2) + 4*hi;
        atomicAdd(&Hl[(db*32 + l31)*HP2 + ql], acc[db][r]);
      }
  }
  __syncthreads();

  // ========= projection: out = (H / l) . W =========
  {
    const int qq = tid >> 3;           // query 0..31
    const int og = (tid & 7) * 8;      // out col group
    f32x4 o0 = (f32x4){0.f,0.f,0.f,0.f};
    f32x4 o1 = (f32x4){0.f,0.f,0.f,0.f};
    for (int d = 0; d < 64; ++d) {
      const float h = Hl[d*HP2 + qq];
      const f32x4* wr = (const f32x4*)&Wl[d*68 + og];
      o0 += h * wr[0];
      o1 += h * wr[1];
    }
    const float inv = 1.0f / Lstar[qq];
    float* op = out + ((size_t)batch * NN + qbase + qq) * DD + og;
    *(f32x4*)(op)     = o0 * inv;
    *(f32x4*)(op + 4) = o1 * inv;
  }
}

extern "C" void kernel_launch(void* const* d_in, const int* in_sizes, int n_in,
                              void* d_out, int out_size, void* d_ws, size_t ws_size,
                              hipStream_t stream) {
  const float* X = (const float*)d_in[0];   // [4, 8192, 64] fp32
  const float* W = (const float*)d_in[1];   // [64, 64] fp32
  float* out = (float*)d_out;               // [4, 8192, 64] fp32

  f16* Xk = (f16*)d_ws;                                    // 4 MiB
  f16* Xv = (f16*)((char*)d_ws + (size_t)4 * NN * DD * 2); // 4 MiB
  prep_f16<<<dim3(512), dim3(256), 0, stream>>>(X, Xk, Xv);
  gconv_attn<<<dim3(1024), dim3(256), 0, stream>>>(X, Xk, Xv, W, out);
}

// Round 10
// 176.216 us; speedup vs baseline: 1.1005x; 1.1005x over previous
//
#include <hip/hip_runtime.h>
#include <math.h>

typedef _Float16 f16;
typedef _Float16 f16x2 __attribute__((ext_vector_type(2)));
typedef _Float16 f16x4 __attribute__((ext_vector_type(4)));
typedef _Float16 f16x8 __attribute__((ext_vector_type(8)));
typedef float    f32x4  __attribute__((ext_vector_type(4)));
typedef float    f32x16 __attribute__((ext_vector_type(16)));

#define PKRTZ(a, b) __builtin_bit_cast(f16x2, __builtin_amdgcn_cvt_pkrtz((a), (b)))
#define MFMA32(a, b, c) __builtin_amdgcn_mfma_f32_32x32x16_f16((a), (b), (c), 0, 0, 0)

#define NN 8192
#define DD 64
#define KT 32
#define NQB 64
#define NWAVES 4               // 4 key-split waves per block (R8 config: best)
#define KPW (NN / NWAVES)      // 2048 keys per wave
#define NTILES (KPW / KT)      // 64

#define LOG2E 1.44269504088896f

// sigma: key-order permutation inside each 32-key tile (self-inverse).
// Makes the 32x32 QK C-layout rows, packed pairwise, directly a valid
// PV A-operand fragment (no cross-lane exchange needed).
__device__ __forceinline__ int sig32(int k) {
  const int g = (k >> 2) & 3;
  return (g == 1 || g == 2) ? (k ^ 12) : k;
}

// ---------------- kernel A: f32 -> fragment-streamed f16 workspaces ----------------
// Workspace layouts are LANE-ORDER STREAMS so kernel B's fragment loads are
// fully coalesced (1024 B contiguous per wave instruction).
//   Xk[b][kt][c(4)][lane(64)][8 f16]   chunk(c,lane): Ksig[l31][c*16+hi*8+j]
//   Xv[b][kt][i(4)][lane(64)][8 f16]   chunk(i=db*2+kh,lane): V[db*32+l31][kh*16+hi*8+j]
__global__ __launch_bounds__(256, 2)
void prep_f16(const float* __restrict__ X, f16* __restrict__ Xk, f16* __restrict__ Xv)
{
  __shared__ f16 Lt[64 * 72];          // 64 keys x 64 d, pitch 72 (natural order)
  const int tid  = threadIdx.x;
  const int b    = blockIdx.x >> 7;
  const int kb64 = (blockIdx.x & 127) * 64;

  // phase 1: coalesced read, cvt, stash in LDS
  {
    const int r = tid >> 2;            // key row 0..63
    const int c = (tid & 3) * 16;      // d col group
    const float* p = X + ((size_t)(b * NN + kb64 + r)) * DD + c;
    const float4 a0 = *(const float4*)(p);
    const float4 a1 = *(const float4*)(p + 4);
    const float4 a2 = *(const float4*)(p + 8);
    const float4 a3 = *(const float4*)(p + 12);
    f16x8 v0, v1;
    v0[0]=(f16)a0.x; v0[1]=(f16)a0.y; v0[2]=(f16)a0.z; v0[3]=(f16)a0.w;
    v0[4]=(f16)a1.x; v0[5]=(f16)a1.y; v0[6]=(f16)a1.z; v0[7]=(f16)a1.w;
    v1[0]=(f16)a2.x; v1[1]=(f16)a2.y; v1[2]=(f16)a2.z; v1[3]=(f16)a2.w;
    v1[4]=(f16)a3.x; v1[5]=(f16)a3.y; v1[6]=(f16)a3.z; v1[7]=(f16)a3.w;
    *(f16x8*)&Lt[r * 72 + c]     = v0;
    *(f16x8*)&Lt[r * 72 + c + 8] = v1;
  }
  __syncthreads();

  // phase 2a: K fragment stream (vector LDS reads, coalesced global writes)
  #pragma unroll
  for (int i = 0; i < 2; ++i) {
    const int gc  = i * 256 + tid;     // 0..511 (2 tiles x 256 chunks)
    const int h   = gc >> 8;           // which 32-key tile of the 64
    const int ci  = gc & 255;          // chunk within tile
    const int c   = ci >> 6;           // d-chunk 0..3
    const int ln  = ci & 63;           // lane
    const int hi  = ln >> 5;
    const int l31 = ln & 31;
    const int row = h * 32 + sig32(l31);
    const f16x8 v = *(const f16x8*)&Lt[row * 72 + c * 16 + hi * 8];
    const int kt  = (kb64 >> 5) + h;
    *(f16x8*)(Xk + ((size_t)(b * (NN/32) + kt)) * 2048 + ci * 8) = v;
  }

  // phase 2b: V fragment stream (transpose via scalar LDS reads)
  #pragma unroll
  for (int i = 0; i < 2; ++i) {
    const int gc  = i * 256 + tid;
    const int h   = gc >> 8;
    const int ci  = gc & 255;
    const int ins = ci >> 6;           // db*2 + kh
    const int db  = ins >> 1;
    const int kh  = ins & 1;
    const int ln  = ci & 63;
    const int hi  = ln >> 5;
    const int l31 = ln & 31;
    union { f16 s[8]; f16x8 v; } u;
    #pragma unroll
    for (int j = 0; j < 8; ++j)
      u.s[j] = Lt[(h*32 + kh*16 + hi*8 + j) * 72 + db*32 + l31];
    const int kt = (kb64 >> 5) + h;
    *(f16x8*)(Xv + ((size_t)(b * (NN/32) + kt)) * 2048 + ci * 8) = u.v;
  }
}

// ---------------- kernel B: attention + projection ----------------
// R8 structure (32x32x16 MFMA, in-register softmax, zero main-loop LDS,
// coalesced fragment streams). NEW (R10): K/V register DOUBLE-buffer with
// 2-tile-ahead prefetch — issue->use distance ~2 tile-walls to cover the
// contended load latency that bounded every previous round (~3600 stall
// cyc/tile at 1-tile-ahead).
#define HL_PITCH 68
#define WL_OFF  (64 * HL_PITCH * 4)      // 17408
#define LST_OFF (2 * 64 * HL_PITCH * 4)  // 34816
#define SMEM_B  (LST_OFF + 64 * 4)       // 35072

__global__ __launch_bounds__(256, 2)
void gconv_attn(const float* __restrict__ X, const f16* __restrict__ Xk,
                const f16* __restrict__ Xv, const float* __restrict__ W,
                float* __restrict__ out)
{
  __shared__ __align__(16) unsigned char smem[SMEM_B];

  const int tid  = threadIdx.x;
  const int lane = tid & 63;
  const int wave = tid >> 6;          // key split 0..3
  const int l31  = lane & 31;
  const int hi   = lane >> 5;

  // ---- XCD-aware decode: one batch per XCD pair (512 = 8 xcd * 64 slots) ----
  const int xcd   = blockIdx.x & 7;
  const int slot  = blockIdx.x >> 3;
  const int batch = xcd >> 1;
  const int qblk  = slot * 2 + (xcd & 1);   // 0..127, bijective
  const int qbase = qblk * NQB;
  const float* Xb = X + (size_t)batch * NN * DD;

  // wave-local bases: lane-order streams (lane*8 folded in)
  const f16* XkW = Xk + ((size_t)batch * (NN/32) + wave * NTILES) * 2048 + lane * 8;
  const f16* XvW = Xv + ((size_t)batch * (NN/32) + wave * NTILES) * 2048 + lane * 8;

  // ---- Q fragments (B-operand: n=l31 query, k=c*16+hi*8+j d), exp2 domain ----
  // -(m2) folded into the MFMA C-initializer minit (f32x16 broadcast).
  f16x8 qf[2][4];
  f32x16 minit[2];
  float lrow[2];
  #pragma unroll
  for (int qb = 0; qb < 2; ++qb) {
    const float* qp = Xb + (size_t)(qbase + qb*32 + l31) * DD + hi*8;
    float nrm = 0.f;
    #pragma unroll
    for (int c = 0; c < 4; ++c) {
      const float4 a = *(const float4*)(qp + c*16);
      const float4 b = *(const float4*)(qp + c*16 + 4);
      float xs[8] = {a.x, a.y, a.z, a.w, b.x, b.y, b.z, b.w};
      f16x8 v;
      #pragma unroll
      for (int e = 0; e < 8; ++e) {
        const f16 kv = (f16)xs[e];
        const f16 qs = (f16)(xs[e] * LOG2E);
        nrm += (float)qs * (float)kv;
        v[e] = qs;
      }
      qf[qb][c] = v;
    }
    nrm += __shfl_xor(nrm, 32);
    const float m2 = nrm + 2.0f;
    #pragma unroll
    for (int e = 0; e < 16; ++e) minit[qb][e] = -m2;
    lrow[qb] = 0.f;
  }

  f32x16 acc[2][2];
  #pragma unroll
  for (int a = 0; a < 2; ++a)
    #pragma unroll
    for (int b = 0; b < 2; ++b)
      #pragma unroll
      for (int e = 0; e < 16; ++e) acc[a][b][e] = 0.f;

  const f16x2 kOnes = (f16x2){(f16)1.0f, (f16)1.0f};

  // double-buffered fragments (A: even tiles, B: odd tiles)
  f16x8 kaA[4], kaB[4];
  f16x8 vbA[2][2], vbB[2][2];

  auto LDK = [&](f16x8 (&ka)[4], int t) {
    const f16* kn = XkW + (size_t)t * 2048;
    #pragma unroll
    for (int c = 0; c < 4; ++c)
      ka[c] = *(const f16x8*)(kn + c * 512);   // 1024 B contiguous per wave
  };
  auto LDV = [&](f16x8 (&vb)[2][2], int t) {
    const f16* vn = XvW + (size_t)t * 2048;
    #pragma unroll
    for (int db = 0; db < 2; ++db)
      #pragma unroll
      for (int kh = 0; kh < 2; ++kh)
        vb[db][kh] = *(const f16x8*)(vn + (db*2 + kh) * 512);
  };

  // softmax+pack: s (C-layout, sigma-ordered keys) -> two PV A-fragments
  auto SMpack = [&](const f32x16& s, float& lr, f16x8& paLo, f16x8& paHi) {
    float p[16];
    #pragma unroll
    for (int r = 0; r < 16; ++r) p[r] = __builtin_amdgcn_exp2f(s[r]);
    union { f16x8 v; f16x2 h[4]; } a, b;
    a.h[0] = PKRTZ(p[0],  p[1]);  a.h[1] = PKRTZ(p[2],  p[3]);
    a.h[2] = PKRTZ(p[4],  p[5]);  a.h[3] = PKRTZ(p[6],  p[7]);
    b.h[0] = PKRTZ(p[8],  p[9]);  b.h[1] = PKRTZ(p[10], p[11]);
    b.h[2] = PKRTZ(p[12], p[13]); b.h[3] = PKRTZ(p[14], p[15]);
    float la = 0.f, lb = 0.f;                  // two 4-deep chains, not one 8-deep
    #pragma unroll
    for (int i = 0; i < 4; ++i) {
      la = __builtin_amdgcn_fdot2(a.h[i], kOnes, la, false);
      lb = __builtin_amdgcn_fdot2(b.h[i], kOnes, lb, false);
    }
    lr += la + lb;
    paLo = a.v; paHi = b.v;
  };

  // one tile: QK(buf) -> prefetch K(t+2 into buf) -> softmax -> PV(buf) ->
  // prefetch V(t+2 into buf). Issue->use distance ~2 tile-walls.
  auto TILE = [&](f16x8 (&ka)[4], f16x8 (&vb)[2][2], int tpf) {
    f32x16 s0 = MFMA32(ka[0], qf[0][0], minit[0]);
    s0 = MFMA32(ka[1], qf[0][1], s0);
    s0 = MFMA32(ka[2], qf[0][2], s0);
    s0 = MFMA32(ka[3], qf[0][3], s0);
    f32x16 s1 = MFMA32(ka[0], qf[1][0], minit[1]);
    s1 = MFMA32(ka[1], qf[1][1], s1);
    s1 = MFMA32(ka[2], qf[1][2], s1);
    s1 = MFMA32(ka[3], qf[1][3], s1);

    LDK(ka, tpf);                 // ka dead; prefetch tile t+2's K

    f16x8 pa00, pa01, pa10, pa11;
    SMpack(s0, lrow[0], pa00, pa01);
    SMpack(s1, lrow[1], pa10, pa11);

    acc[0][0] = MFMA32(pa00, vb[0][0], acc[0][0]);
    acc[0][0] = MFMA32(pa01, vb[0][1], acc[0][0]);
    acc[0][1] = MFMA32(pa00, vb[1][0], acc[0][1]);
    acc[0][1] = MFMA32(pa01, vb[1][1], acc[0][1]);
    acc[1][0] = MFMA32(pa10, vb[0][0], acc[1][0]);
    acc[1][0] = MFMA32(pa11, vb[0][1], acc[1][0]);
    acc[1][1] = MFMA32(pa10, vb[1][0], acc[1][1]);
    acc[1][1] = MFMA32(pa11, vb[1][1], acc[1][1]);

    LDV(vb, tpf);                 // vb dead; prefetch tile t+2's V
  };

  // ---- prologue: fill both buffers ----
  LDK(kaA, 0); LDV(vbA, 0);
  LDK(kaB, 1); LDV(vbB, 1);

  // ---- main loop, unroll-2 (NTILES = 64, even) ----
  for (int t = 0; t < NTILES; t += 2) {
    const int ta = (t + 2 < NTILES) ? t + 2 : NTILES - 1;  // clamp: tail reloads are unused
    const int tb = (t + 3 < NTILES) ? t + 3 : NTILES - 1;
    TILE(kaA, vbA, ta);           // tile t   (buffer A)
    TILE(kaB, vbB, tb);           // tile t+1 (buffer B)
  }

  // ========= merge across 4 key-split waves (shared m2: plain sums) =========
  __syncthreads();
  float* Hl    = (float*)smem;
  float* Wl    = (float*)(smem + WL_OFF);
  float* Lstar = (float*)(smem + LST_OFF);

  for (int i = tid; i < 64*HL_PITCH; i += 256) Hl[i] = 0.f;
  for (int i = tid; i < 64*64; i += 256) Wl[(i >> 6)*HL_PITCH + (i & 63)] = W[i];
  if (tid < 64) Lstar[tid] = 0.f;
  __syncthreads();

  // acc C-layout: col = l31 = d (within 32-block), row ql = (r&3)+8*(r>>2)+4*hi
  #pragma unroll
  for (int qb = 0; qb < 2; ++qb) {
    float lr = lrow[qb];
    lr += __shfl_xor(lr, 32);
    if (lane < 32) atomicAdd(&Lstar[qb*32 + lane], lr);
    #pragma unroll
    for (int db = 0; db < 2; ++db)
      #pragma unroll
      for (int r = 0; r < 16; ++r) {
        const int ql = (r & 3) + 8*(r >> 2) + 4*hi;
        atomicAdd(&Hl[(db*32 + l31)*HL_PITCH + qb*32 + ql], acc[qb][db][r]);
      }
  }
  __syncthreads();

  // ========= projection: out = (H / l) . W =========
  {
    const int qq = tid >> 2;
    const int og = (tid & 3) * 16;
    f32x4 o[4];
    #pragma unroll
    for (int i = 0; i < 4; ++i) o[i] = (f32x4){0.f,0.f,0.f,0.f};
    for (int d = 0; d < 64; ++d) {
      const float h = Hl[d*HL_PITCH + qq];
      const f32x4* wr = (const f32x4*)&Wl[d*HL_PITCH + og];
      #pragma unroll
      for (int i = 0; i < 4; ++i) o[i] += h * wr[i];
    }
    const float inv = 1.0f / Lstar[qq];
    float* op = out + ((size_t)batch * NN + qbase + qq) * DD + og;
    #pragma unroll
    for (int i = 0; i < 4; ++i)
      *(f32x4*)(op + i*4) = o[i] * inv;
  }
}

extern "C" void kernel_launch(void* const* d_in, const int* in_sizes, int n_in,
                              void* d_out, int out_size, void* d_ws, size_t ws_size,
                              hipStream_t stream) {
  const float* X = (const float*)d_in[0];   // [4, 8192, 64] fp32
  const float* W = (const float*)d_in[1];   // [64, 64] fp32
  float* out = (float*)d_out;               // [4, 8192, 64] fp32

  f16* Xk = (f16*)d_ws;                                    // 4 MiB
  f16* Xv = (f16*)((char*)d_ws + (size_t)4 * NN * DD * 2); // 4 MiB
  prep_f16<<<dim3(512), dim3(256), 0, stream>>>(X, Xk, Xv);
  gconv_attn<<<dim3(512), dim3(256), 0, stream>>>(X, Xk, Xv, W, out);
}

// Round 11
// 164.704 us; speedup vs baseline: 1.1774x; 1.0699x over previous
//
#include <hip/hip_runtime.h>
#include <math.h>

typedef _Float16 f16;
typedef _Float16 f16x2 __attribute__((ext_vector_type(2)));
typedef _Float16 f16x4 __attribute__((ext_vector_type(4)));
typedef _Float16 f16x8 __attribute__((ext_vector_type(8)));
typedef float    f32x4  __attribute__((ext_vector_type(4)));
typedef float    f32x16 __attribute__((ext_vector_type(16)));

#define PKRTZ(a, b) __builtin_bit_cast(f16x2, __builtin_amdgcn_cvt_pkrtz((a), (b)))
#define MFMA32(a, b, c) __builtin_amdgcn_mfma_f32_32x32x16_f16((a), (b), (c), 0, 0, 0)

#define NN 8192
#define DD 64
#define KT 32
#define NQB 64
#define NWAVES 4               // 4 key-split waves per block
#define KPW (NN / NWAVES)      // 2048 keys per wave
#define NTILES (KPW / KT)      // 64

#define LOG2E 1.44269504088896f

// sigma: key-order permutation inside each 32-key tile (self-inverse).
// Makes the 32x32 QK C-layout rows, packed pairwise, directly a valid
// PV A-operand fragment (no cross-lane exchange needed).
__device__ __forceinline__ int sig32(int k) {
  const int g = (k >> 2) & 3;
  return (g == 1 || g == 2) ? (k ^ 12) : k;
}

// ---------------- kernel A: f32 -> fragment-streamed f16 workspaces ----------------
// Workspace layouts are LANE-ORDER STREAMS so kernel B's fragment loads are
// fully coalesced (1024 B contiguous per wave instruction).
//   Xk[b][kt][c(4)][lane(64)][8 f16]   chunk(c,lane): Ksig[l31][c*16+hi*8+j]
//   Xv[b][kt][i(4)][lane(64)][8 f16]   chunk(i=db*2+kh,lane): V[db*32+l31][kh*16+hi*8+j]
__global__ __launch_bounds__(256, 2)
void prep_f16(const float* __restrict__ X, f16* __restrict__ Xk, f16* __restrict__ Xv)
{
  __shared__ f16 Lt[64 * 72];          // 64 keys x 64 d, pitch 72 (natural order)
  const int tid  = threadIdx.x;
  const int b    = blockIdx.x >> 7;
  const int kb64 = (blockIdx.x & 127) * 64;

  // phase 1: coalesced read, cvt, stash in LDS
  {
    const int r = tid >> 2;            // key row 0..63
    const int c = (tid & 3) * 16;      // d col group
    const float* p = X + ((size_t)(b * NN + kb64 + r)) * DD + c;
    const float4 a0 = *(const float4*)(p);
    const float4 a1 = *(const float4*)(p + 4);
    const float4 a2 = *(const float4*)(p + 8);
    const float4 a3 = *(const float4*)(p + 12);
    f16x8 v0, v1;
    v0[0]=(f16)a0.x; v0[1]=(f16)a0.y; v0[2]=(f16)a0.z; v0[3]=(f16)a0.w;
    v0[4]=(f16)a1.x; v0[5]=(f16)a1.y; v0[6]=(f16)a1.z; v0[7]=(f16)a1.w;
    v1[0]=(f16)a2.x; v1[1]=(f16)a2.y; v1[2]=(f16)a2.z; v1[3]=(f16)a2.w;
    v1[4]=(f16)a3.x; v1[5]=(f16)a3.y; v1[6]=(f16)a3.z; v1[7]=(f16)a3.w;
    *(f16x8*)&Lt[r * 72 + c]     = v0;
    *(f16x8*)&Lt[r * 72 + c + 8] = v1;
  }
  __syncthreads();

  // phase 2a: K fragment stream (vector LDS reads, coalesced global writes)
  #pragma unroll
  for (int i = 0; i < 2; ++i) {
    const int gc  = i * 256 + tid;     // 0..511 (2 tiles x 256 chunks)
    const int h   = gc >> 8;           // which 32-key tile of the 64
    const int ci  = gc & 255;          // chunk within tile
    const int c   = ci >> 6;           // d-chunk 0..3
    const int ln  = ci & 63;           // lane
    const int hi  = ln >> 5;
    const int l31 = ln & 31;
    const int row = h * 32 + sig32(l31);
    const f16x8 v = *(const f16x8*)&Lt[row * 72 + c * 16 + hi * 8];
    const int kt  = (kb64 >> 5) + h;
    *(f16x8*)(Xk + ((size_t)(b * (NN/32) + kt)) * 2048 + ci * 8) = v;
  }

  // phase 2b: V fragment stream (transpose via scalar LDS reads)
  #pragma unroll
  for (int i = 0; i < 2; ++i) {
    const int gc  = i * 256 + tid;
    const int h   = gc >> 8;
    const int ci  = gc & 255;
    const int ins = ci >> 6;           // db*2 + kh
    const int db  = ins >> 1;
    const int kh  = ins & 1;
    const int ln  = ci & 63;
    const int hi  = ln >> 5;
    const int l31 = ln & 31;
    union { f16 s[8]; f16x8 v; } u;
    #pragma unroll
    for (int j = 0; j < 8; ++j)
      u.s[j] = Lt[(h*32 + kh*16 + hi*8 + j) * 72 + db*32 + l31];
    const int kt = (kb64 >> 5) + h;
    *(f16x8*)(Xv + ((size_t)(b * (NN/32) + kt)) * 2048 + ci * 8) = u.v;
  }
}

// ---------------- kernel B: attention + projection ----------------
// R10 base (32x32x16 MFMA, in-register softmax, coalesced fragment streams).
// NEW (R11): 1-tile softmax/PV pipeline — loop body is QK(t) || SMPV(t-1),
// with S-scores held in registers (sE/sO by tile parity, static indices).
// The 8 QK MFMAs of tile t are independent of SMPV(t-1)'s VALU, giving the
// scheduler adjacent independent MFMA+VALU work (fixes the measured 52%
// both-pipes-idle phase alternation). minit dropped (explicit s-m2 subtract)
// and ka single-buffered to fund the +64 S registers.
#define HL_PITCH 68
#define WL_OFF  (64 * HL_PITCH * 4)      // 17408
#define LST_OFF (2 * 64 * HL_PITCH * 4)  // 34816
#define SMEM_B  (LST_OFF + 64 * 4)       // 35072

__global__ __launch_bounds__(256, 2)
void gconv_attn(const float* __restrict__ X, const f16* __restrict__ Xk,
                const f16* __restrict__ Xv, const float* __restrict__ W,
                float* __restrict__ out)
{
  __shared__ __align__(16) unsigned char smem[SMEM_B];

  const int tid  = threadIdx.x;
  const int lane = tid & 63;
  const int wave = tid >> 6;          // key split 0..3
  const int l31  = lane & 31;
  const int hi   = lane >> 5;

  // ---- XCD-aware decode: one batch per XCD pair (512 = 8 xcd * 64 slots) ----
  const int xcd   = blockIdx.x & 7;
  const int slot  = blockIdx.x >> 3;
  const int batch = xcd >> 1;
  const int qblk  = slot * 2 + (xcd & 1);   // 0..127, bijective
  const int qbase = qblk * NQB;
  const float* Xb = X + (size_t)batch * NN * DD;

  // wave-local bases: lane-order streams (lane*8 folded in)
  const f16* XkW = Xk + ((size_t)batch * (NN/32) + wave * NTILES) * 2048 + lane * 8;
  const f16* XvW = Xv + ((size_t)batch * (NN/32) + wave * NTILES) * 2048 + lane * 8;

  // ---- Q fragments (B-operand: n=l31 query, k=c*16+hi*8+j d), exp2 domain ----
  f16x8 qf[2][4];
  float m2[2];
  float lrow[2];
  #pragma unroll
  for (int qb = 0; qb < 2; ++qb) {
    const float* qp = Xb + (size_t)(qbase + qb*32 + l31) * DD + hi*8;
    float nrm = 0.f;
    #pragma unroll
    for (int c = 0; c < 4; ++c) {
      const float4 a = *(const float4*)(qp + c*16);
      const float4 b = *(const float4*)(qp + c*16 + 4);
      float xs[8] = {a.x, a.y, a.z, a.w, b.x, b.y, b.z, b.w};
      f16x8 v;
      #pragma unroll
      for (int e = 0; e < 8; ++e) {
        const f16 kv = (f16)xs[e];
        const f16 qs = (f16)(xs[e] * LOG2E);
        nrm += (float)qs * (float)kv;
        v[e] = qs;
      }
      qf[qb][c] = v;
    }
    nrm += __shfl_xor(nrm, 32);
    m2[qb] = nrm + 2.0f;
    lrow[qb] = 0.f;
  }

  f32x16 acc[2][2];
  #pragma unroll
  for (int a = 0; a < 2; ++a)
    #pragma unroll
    for (int b = 0; b < 2; ++b)
      #pragma unroll
      for (int e = 0; e < 16; ++e) acc[a][b][e] = 0.f;

  f32x16 z16;
  #pragma unroll
  for (int e = 0; e < 16; ++e) z16[e] = 0.f;

  const f16x2 kOnes = (f16x2){(f16)1.0f, (f16)1.0f};

  f16x8 ka[4];                 // K A-operand (single buffer)
  f16x8 vbA[2][2], vbB[2][2];  // V B-operand double buffer

  auto LDK = [&](int t) {
    const f16* kn = XkW + (size_t)t * 2048;
    #pragma unroll
    for (int c = 0; c < 4; ++c)
      ka[c] = *(const f16x8*)(kn + c * 512);   // 1024 B contiguous per wave
  };
  auto LDV = [&](f16x8 (&vb)[2][2], int t) {
    const f16* vn = XvW + (size_t)t * 2048;
    #pragma unroll
    for (int db = 0; db < 2; ++db)
      #pragma unroll
      for (int kh = 0; kh < 2; ++kh)
        vb[db][kh] = *(const f16x8*)(vn + (db*2 + kh) * 512);
  };

  // QK: consumes ka, produces scores for both q-blocks
  auto QK = [&](f32x16& s0, f32x16& s1) {
    s0 = MFMA32(ka[0], qf[0][0], z16);
    s0 = MFMA32(ka[1], qf[0][1], s0);
    s0 = MFMA32(ka[2], qf[0][2], s0);
    s0 = MFMA32(ka[3], qf[0][3], s0);
    s1 = MFMA32(ka[0], qf[1][0], z16);
    s1 = MFMA32(ka[1], qf[1][1], s1);
    s1 = MFMA32(ka[2], qf[1][2], s1);
    s1 = MFMA32(ka[3], qf[1][3], s1);
  };

  // softmax+pack one q-block: s (sigma-ordered keys) -> two PV A-fragments
  auto SMpack = [&](const f32x16& s, float m2v, float& lr, f16x8& paLo, f16x8& paHi) {
    float p[16];
    #pragma unroll
    for (int r = 0; r < 16; ++r) p[r] = __builtin_amdgcn_exp2f(s[r] - m2v);
    union { f16x8 v; f16x2 h[4]; } a, b;
    a.h[0] = PKRTZ(p[0],  p[1]);  a.h[1] = PKRTZ(p[2],  p[3]);
    a.h[2] = PKRTZ(p[4],  p[5]);  a.h[3] = PKRTZ(p[6],  p[7]);
    b.h[0] = PKRTZ(p[8],  p[9]);  b.h[1] = PKRTZ(p[10], p[11]);
    b.h[2] = PKRTZ(p[12], p[13]); b.h[3] = PKRTZ(p[14], p[15]);
    float la = 0.f, lb = 0.f;
    #pragma unroll
    for (int i = 0; i < 4; ++i) {
      la = __builtin_amdgcn_fdot2(a.h[i], kOnes, la, false);
      lb = __builtin_amdgcn_fdot2(b.h[i], kOnes, lb, false);
    }
    lr += la + lb;
    paLo = a.v; paHi = b.v;
  };

  // softmax + PV for one tile (consumes s-pair and the tile's V buffer)
  auto SMPV = [&](const f32x16& s0, const f32x16& s1, const f16x8 (&vb)[2][2]) {
    f16x8 pa0, pa1;
    SMpack(s0, m2[0], lrow[0], pa0, pa1);
    acc[0][0] = MFMA32(pa0, vb[0][0], acc[0][0]);
    acc[0][0] = MFMA32(pa1, vb[0][1], acc[0][0]);
    acc[0][1] = MFMA32(pa0, vb[1][0], acc[0][1]);
    acc[0][1] = MFMA32(pa1, vb[1][1], acc[0][1]);
    f16x8 pb0, pb1;
    SMpack(s1, m2[1], lrow[1], pb0, pb1);
    acc[1][0] = MFMA32(pb0, vb[0][0], acc[1][0]);
    acc[1][0] = MFMA32(pb1, vb[0][1], acc[1][0]);
    acc[1][1] = MFMA32(pb0, vb[1][0], acc[1][1]);
    acc[1][1] = MFMA32(pb1, vb[1][1], acc[1][1]);
  };

  // ---- pipelined main loop: QK(t) || SMPV(t-1), S in sE/sO by parity ----
  f32x16 sE0, sE1, sO0, sO1;
  LDK(0);
  LDV(vbA, 0);
  LDV(vbB, 1);
  QK(sE0, sE1);                 // tile 0
  LDK(1);
  for (int t = 1; t < NTILES - 1; t += 2) {
    QK(sO0, sO1);               // tile t (odd)   — MFMA, independent of SMPV below
    LDK(t + 1);
    SMPV(sE0, sE1, vbA);        // tile t-1 (even) — VALU+MFMA
    LDV(vbA, t + 1);
    QK(sE0, sE1);               // tile t+1 (even)
    LDK(t + 2);
    SMPV(sO0, sO1, vbB);        // tile t (odd)
    LDV(vbB, t + 2);
  }
  QK(sO0, sO1);                 // tile NTILES-1
  SMPV(sE0, sE1, vbA);          // tile NTILES-2
  SMPV(sO0, sO1, vbB);          // tile NTILES-1

  // ========= merge across 4 key-split waves (shared m2: plain sums) =========
  __syncthreads();
  float* Hl    = (float*)smem;
  float* Wl    = (float*)(smem + WL_OFF);
  float* Lstar = (float*)(smem + LST_OFF);

  for (int i = tid; i < 64*HL_PITCH; i += 256) Hl[i] = 0.f;
  for (int i = tid; i < 64*64; i += 256) Wl[(i >> 6)*HL_PITCH + (i & 63)] = W[i];
  if (tid < 64) Lstar[tid] = 0.f;
  __syncthreads();

  // acc C-layout: col = l31 = d (within 32-block), row ql = (r&3)+8*(r>>2)+4*hi
  #pragma unroll
  for (int qb = 0; qb < 2; ++qb) {
    float lr = lrow[qb];
    lr += __shfl_xor(lr, 32);
    if (lane < 32) atomicAdd(&Lstar[qb*32 + lane], lr);
    #pragma unroll
    for (int db = 0; db < 2; ++db)
      #pragma unroll
      for (int r = 0; r < 16; ++r) {
        const int ql = (r & 3) + 8*(r >> 2) + 4*hi;
        atomicAdd(&Hl[(db*32 + l31)*HL_PITCH + qb*32 + ql], acc[qb][db][r]);
      }
  }
  __syncthreads();

  // ========= projection: out = (H / l) . W =========
  {
    const int qq = tid >> 2;
    const int og = (tid & 3) * 16;
    f32x4 o[4];
    #pragma unroll
    for (int i = 0; i < 4; ++i) o[i] = (f32x4){0.f,0.f,0.f,0.f};
    for (int d = 0; d < 64; ++d) {
      const float h = Hl[d*HL_PITCH + qq];
      const f32x4* wr = (const f32x4*)&Wl[d*HL_PITCH + og];
      #pragma unroll
      for (int i = 0; i < 4; ++i) o[i] += h * wr[i];
    }
    const float inv = 1.0f / Lstar[qq];
    float* op = out + ((size_t)batch * NN + qbase + qq) * DD + og;
    #pragma unroll
    for (int i = 0; i < 4; ++i)
      *(f32x4*)(op + i*4) = o[i] * inv;
  }
}

extern "C" void kernel_launch(void* const* d_in, const int* in_sizes, int n_in,
                              void* d_out, int out_size, void* d_ws, size_t ws_size,
                              hipStream_t stream) {
  const float* X = (const float*)d_in[0];   // [4, 8192, 64] fp32
  const float* W = (const float*)d_in[1];   // [64, 64] fp32
  float* out = (float*)d_out;               // [4, 8192, 64] fp32

  f16* Xk = (f16*)d_ws;                                    // 4 MiB
  f16* Xv = (f16*)((char*)d_ws + (size_t)4 * NN * DD * 2); // 4 MiB
  prep_f16<<<dim3(512), dim3(256), 0, stream>>>(X, Xk, Xv);
  gconv_attn<<<dim3(512), dim3(256), 0, stream>>>(X, Xk, Xv, W, out);
}